// Round 1
// baseline (1028.398 us; speedup 1.0000x reference)
//
#include <hip/hip_runtime.h>

typedef __bf16 bf16x8 __attribute__((ext_vector_type(8)));
typedef __bf16 bf16x4 __attribute__((ext_vector_type(4)));
typedef float  f32x4  __attribute__((ext_vector_type(4)));
typedef int    i32x4  __attribute__((ext_vector_type(4)));

#define BB 1024
#define LL 50
#define DD 128
#define KG 50
#define VV 100000

__device__ __forceinline__ float fsig(float x) {
  x = fminf(fmaxf(x, -20.f), 20.f);
  return 1.f / (1.f + __expf(-x));
}
__device__ __forceinline__ float ftanh(float x) {
  x = fminf(fmaxf(x, -15.f), 15.f);
  float e = __expf(-2.f * x);
  return (1.f - e) / (1.f + e);
}

// ---------------- kg_map column stats (mean, rstd over V items) ----------------
__global__ void kg_stats_kernel(const float* __restrict__ kg, float* __restrict__ sums)
{
  __shared__ float ssum[KG], ssq[KG];
  const int tid = threadIdx.x;
  if (tid < KG) { ssum[tid] = 0.f; ssq[tid] = 0.f; }
  __syncthreads();
  const int total = VV * KG;
  for (int i = blockIdx.x * 256 + tid; i < total; i += gridDim.x * 256) {
    float v = kg[i];
    int col = i % KG;
    atomicAdd(&ssum[col], v);
    atomicAdd(&ssq[col], v * v);
  }
  __syncthreads();
  if (tid < KG) {
    atomicAdd(&sums[tid], ssum[tid]);
    atomicAdd(&sums[KG + tid], ssq[tid]);
  }
}

__global__ void kg_finalize_kernel(const float* __restrict__ sums, float* __restrict__ musd)
{
  int k = threadIdx.x;
  if (k < KG) {
    float mu  = sums[k] * (1.f / (float)VV);
    float var = sums[KG + k] * (1.f / (float)VV) - mu * mu;
    musd[k] = mu;
    musd[KG + k] = rsqrtf(var + 1e-5f);
  }
}

// ---------------- GRU: 64 blocks x 16 batch rows, weights in MFMA register frags ----------------
// wave w owns col-tiles ct = w + 4j, j=0..5  (j=0,1: r-gate, 2,3: z-gate, 4,5: n-gate)
__global__ __launch_bounds__(256, 1) void gru_kernel(
    const int* __restrict__ seq, const int* __restrict__ tlen,
    const float* __restrict__ emb,
    const float* __restrict__ Wih, const float* __restrict__ Whh,
    const float* __restrict__ bih, const float* __restrict__ bhh,
    __bf16* __restrict__ mlp_in)
{
  __shared__ float h_lds[16][132];     // pad to 132 words: 2-way banks only
  __shared__ int   seq_lds[LL][16];
  const int tid  = threadIdx.x;
  const int wave = tid >> 6, lane = tid & 63;
  const int g = lane >> 4, lr = lane & 15;
  const int b0 = blockIdx.x << 4;

  for (int i = tid; i < LL * 16; i += 256) {
    int t = i >> 4, r = i & 15;
    seq_lds[t][r] = seq[(b0 + r) * LL + t];
  }
  for (int i = tid; i < 16 * 132; i += 256) (&h_lds[0][0])[i] = 0.f;

  // preload weight fragments (register resident for all 50 steps)
  bf16x8 wf[6][4], hf[6][4];
  float bx[6], bh2[6];
#pragma unroll
  for (int j = 0; j < 6; ++j) {
    const int col = (wave + 4 * j) * 16 + lr;
    bx[j]  = bih[col];
    bh2[j] = bhh[col];
#pragma unroll
    for (int kt = 0; kt < 4; ++kt) {
      const float* pw = Wih + col * DD + kt * 32 + g * 8;
      const float* ph = Whh + col * DD + kt * 32 + g * 8;
      bf16x8 a, b;
#pragma unroll
      for (int i = 0; i < 8; ++i) { a[i] = (__bf16)pw[i]; b[i] = (__bf16)ph[i]; }
      wf[j][kt] = a; hf[j][kt] = b;
    }
  }
  i32x4 lenv = *(const i32x4*)(tlen + b0 + g * 4);
  float hreg[2][4] = {{0.f,0.f,0.f,0.f},{0.f,0.f,0.f,0.f}};
  __syncthreads();

  for (int t = 0; t < LL; ++t) {
    // issue x gathers early (latency hides under gh phase)
    const int idx = seq_lds[t][lr];
    const float* xrow = emb + (size_t)idx * DD;
    f32x4 xv[4][2];
#pragma unroll
    for (int kt = 0; kt < 4; ++kt) {
      xv[kt][0] = *(const f32x4*)(xrow + kt * 32 + g * 8);
      xv[kt][1] = *(const f32x4*)(xrow + kt * 32 + g * 8 + 4);
    }
    // gh = h @ Whh^T + bhh
    f32x4 ah[6];
#pragma unroll
    for (int j = 0; j < 6; ++j) { f32x4 v = {bh2[j],bh2[j],bh2[j],bh2[j]}; ah[j] = v; }
#pragma unroll
    for (int kt = 0; kt < 4; ++kt) {
      const float* hp = &h_lds[lr][kt * 32 + g * 8];
      f32x4 h0 = *(const f32x4*)hp;
      f32x4 h1 = *(const f32x4*)(hp + 4);
      bf16x8 hfrag;
#pragma unroll
      for (int i = 0; i < 4; ++i) { hfrag[i] = (__bf16)h0[i]; hfrag[i+4] = (__bf16)h1[i]; }
#pragma unroll
      for (int j = 0; j < 6; ++j)
        ah[j] = __builtin_amdgcn_mfma_f32_16x16x32_bf16(hfrag, hf[j][kt], ah[j], 0, 0, 0);
    }
    __syncthreads();   // all h reads done before any h write
    // gx = x @ Wih^T + bih
    f32x4 ax[6];
#pragma unroll
    for (int j = 0; j < 6; ++j) { f32x4 v = {bx[j],bx[j],bx[j],bx[j]}; ax[j] = v; }
#pragma unroll
    for (int kt = 0; kt < 4; ++kt) {
      bf16x8 xfrag;
#pragma unroll
      for (int i = 0; i < 4; ++i) { xfrag[i] = (__bf16)xv[kt][0][i]; xfrag[i+4] = (__bf16)xv[kt][1][i]; }
#pragma unroll
      for (int j = 0; j < 6; ++j)
        ax[j] = __builtin_amdgcn_mfma_f32_16x16x32_bf16(xfrag, wf[j][kt], ax[j], 0, 0, 0);
    }
    // gates (r,z,n columns align within lane across tile-pairs)
#pragma unroll
    for (int q = 0; q < 2; ++q) {
      const int hcol = q * 64 + wave * 16 + lr;
#pragma unroll
      for (int r = 0; r < 4; ++r) {
        float rg = fsig(ax[q][r] + ah[q][r]);
        float zg = fsig(ax[q+2][r] + ah[q+2][r]);
        float ng = ftanh(ax[q+4][r] + rg * ah[q+4][r]);
        float hn = (1.f - zg) * ng + zg * hreg[q][r];
        if (t < lenv[r]) hreg[q][r] = hn;   // packed-seq mask: freeze h past train_len
        h_lds[g * 4 + r][hcol] = hreg[q][r];
      }
    }
    __syncthreads();
  }
  // write final h (bf16) into mlp_in[:, 0:128]
  const int r = tid >> 4, c0 = (tid & 15) * 8;
  __bf16* dst = mlp_in + (size_t)(b0 + r) * 256 + c0;
#pragma unroll
  for (int i = 0; i < 8; ++i) dst[i] = (__bf16)h_lds[r][c0 + i];
}

// ---------------- batch_kg + mlp_history, fills mlp_in[:, 128:256] ----------------
__global__ __launch_bounds__(64) void bk_kernel(
    const int* __restrict__ seq, const int* __restrict__ tlen,
    const float* __restrict__ kg, const float* __restrict__ musd,
    const float* __restrict__ mW, const float* __restrict__ mb,
    __bf16* __restrict__ mlp_in)
{
  const int b = blockIdx.x;
  const int lane = threadIdx.x;
  int myidx = 0;
  if (lane < LL) myidx = seq[b * LL + lane];
  float s = 0.f;
  for (int t = 0; t < LL; ++t) {
    int idx = __shfl(myidx, t, 64);
    if (lane < KG) s += kg[(size_t)idx * KG + lane];
  }
  float bk = 0.f;
  if (lane < KG) {
    float mu = musd[lane], rstd = musd[KG + lane];
    bk = rstd * (s - (float)LL * mu) / (float)tlen[b];
  }
  float k2 = (lane < KG) ? mb[lane] : 0.f;
  for (int i = 0; i < KG; ++i) {
    float bi = __shfl(bk, i, 64);
    if (lane < KG) k2 += bi * mW[lane * KG + i];
  }
  __bf16* row = mlp_in + (size_t)b * 256;
  if (lane < KG) { row[DD + lane] = (__bf16)bk; row[DD + KG + lane] = (__bf16)k2; }
  if (lane < 28) row[228 + lane] = (__bf16)0.f;   // zero-pad K 228..255
}

// ---------------- MLP: hidden = tanh(mlp_in @ mlp_W^T + mlp_b), bf16 out ----------------
__global__ __launch_bounds__(256) void mlp_kernel(
    const __bf16* __restrict__ mlp_in, const float* __restrict__ W,
    const float* __restrict__ bias, __bf16* __restrict__ hidden)
{
  __shared__ __bf16 As[32][264];
  __shared__ __bf16 Bs[64][264];
  const int tid = threadIdx.x;
  const int mblk = blockIdx.x >> 2, nblk = blockIdx.x & 3;
#pragma unroll
  for (int it = 0; it < 4; ++it) {
    int c = it * 256 + tid;
    int row = c >> 5, off = (c & 31) * 8;
    *(bf16x8*)&As[row][off] = *(const bf16x8*)(mlp_in + (size_t)(mblk*32+row)*256 + off);
  }
  for (int i = tid; i < 64 * 256; i += 256) {
    int row = i >> 8, k = i & 255;
    float v = (k < 228) ? W[(nblk*64+row)*228 + k] : 0.f;
    Bs[row][k] = (__bf16)v;
  }
  __syncthreads();
  const int wave = tid >> 6, lane = tid & 63, g = lane >> 4, lr = lane & 15;
  const int mt = wave & 1, nh = wave >> 1;
  f32x4 acc[2];
#pragma unroll
  for (int c2 = 0; c2 < 2; ++c2) {
    float bb = bias[nblk*64 + (nh*2+c2)*16 + lr];
    f32x4 v = {bb,bb,bb,bb}; acc[c2] = v;
  }
#pragma unroll
  for (int kt = 0; kt < 8; ++kt) {
    bf16x8 a = *(const bf16x8*)&As[mt*16 + lr][kt*32 + g*8];
#pragma unroll
    for (int c2 = 0; c2 < 2; ++c2) {
      bf16x8 b = *(const bf16x8*)&Bs[(nh*2+c2)*16 + lr][kt*32 + g*8];
      acc[c2] = __builtin_amdgcn_mfma_f32_16x16x32_bf16(a, b, acc[c2], 0, 0, 0);
    }
  }
#pragma unroll
  for (int c2 = 0; c2 < 2; ++c2)
#pragma unroll
    for (int r = 0; r < 4; ++r) {
      int row = mblk*32 + mt*16 + g*4 + r;
      int col = nblk*64 + (nh*2+c2)*16 + lr;
      hidden[(size_t)row*256 + col] = (__bf16)ftanh(acc[c2][r]);
    }
}

// ---------------- fc: out[1024,100000] = hidden @ fc_W^T + fc_b ----------------
// BM=128, BN=160, BK=64 staged; grid 8 x 625; 41.5KB LDS -> 2 blocks/CU
__global__ __launch_bounds__(256, 2) void fc_kernel(
    const __bf16* __restrict__ hidden, const float* __restrict__ W,
    const float* __restrict__ bias, float* __restrict__ out)
{
  __shared__ __bf16 As[128][72];
  __shared__ __bf16 Bs[160][72];
  const int tid = threadIdx.x;
  const int m = blockIdx.x & 7;
  const int n = blockIdx.x >> 3;
  const int wave = tid >> 6, lane = tid & 63, g = lane >> 4, lr = lane & 15;
  f32x4 acc[2][10];
#pragma unroll
  for (int ct = 0; ct < 10; ++ct) {
    float bb = bias[n*160 + ct*16 + lr];
    f32x4 v = {bb,bb,bb,bb};
    acc[0][ct] = v; acc[1][ct] = v;
  }
  for (int ks = 0; ks < 4; ++ks) {
    __syncthreads();
#pragma unroll
    for (int it = 0; it < 4; ++it) {           // A slab: 128 x 64 bf16
      int c = it * 256 + tid;
      int row = c >> 3, off = (c & 7) * 8;
      *(bf16x8*)&As[row][off] =
          *(const bf16x8*)(hidden + (size_t)(m*128+row)*256 + ks*64 + off);
    }
#pragma unroll
    for (int it = 0; it < 10; ++it) {          // B slab: 160 x 64 f32 -> bf16
      int c = it * 256 + tid;
      int row = c >> 4, k4 = (c & 15) * 4;
      f32x4 v = *(const f32x4*)(W + (size_t)(n*160+row)*256 + ks*64 + k4);
      bf16x4 bv;
#pragma unroll
      for (int i = 0; i < 4; ++i) bv[i] = (__bf16)v[i];
      *(bf16x4*)&Bs[row][k4] = bv;
    }
    __syncthreads();
#pragma unroll
    for (int kt = 0; kt < 2; ++kt) {
      bf16x8 a0 = *(const bf16x8*)&As[wave*32 + lr][kt*32 + g*8];
      bf16x8 a1 = *(const bf16x8*)&As[wave*32 + 16 + lr][kt*32 + g*8];
#pragma unroll
      for (int ct = 0; ct < 10; ++ct) {
        bf16x8 b = *(const bf16x8*)&Bs[ct*16 + lr][kt*32 + g*8];
        acc[0][ct] = __builtin_amdgcn_mfma_f32_16x16x32_bf16(a0, b, acc[0][ct], 0, 0, 0);
        acc[1][ct] = __builtin_amdgcn_mfma_f32_16x16x32_bf16(a1, b, acc[1][ct], 0, 0, 0);
      }
    }
  }
#pragma unroll
  for (int mt = 0; mt < 2; ++mt)
#pragma unroll
    for (int ct = 0; ct < 10; ++ct)
#pragma unroll
      for (int r = 0; r < 4; ++r) {
        size_t row = (size_t)(m*128 + wave*32 + mt*16 + g*4 + r);
        size_t col = (size_t)n*160 + ct*16 + lr;
        __builtin_nontemporal_store(acc[mt][ct][r], out + row * (size_t)VV + col);
      }
}

extern "C" void kernel_launch(void* const* d_in, const int* in_sizes, int n_in,
                              void* d_out, int out_size, void* d_ws, size_t ws_size,
                              hipStream_t stream) {
  const int*   seq      = (const int*)d_in[0];
  const int*   tlen     = (const int*)d_in[1];
  const float* item_emb = (const float*)d_in[2];
  const float* kg_map   = (const float*)d_in[3];
  const float* Wih      = (const float*)d_in[4];
  const float* Whh      = (const float*)d_in[5];
  const float* bih      = (const float*)d_in[6];
  const float* bhh      = (const float*)d_in[7];
  const float* mlphW    = (const float*)d_in[8];
  const float* mlphb    = (const float*)d_in[9];
  const float* mlpW     = (const float*)d_in[10];
  const float* mlpb     = (const float*)d_in[11];
  const float* fcW      = (const float*)d_in[12];
  const float* fcb      = (const float*)d_in[13];
  float* out = (float*)d_out;

  char* ws = (char*)d_ws;
  float* stats  = (float*)ws;               // 100 floats: sums, sqsums
  float* musd   = (float*)(ws + 512);       // 100 floats: mu, rstd
  __bf16* mlp_in = (__bf16*)(ws + 4096);                 // [1024][256]
  __bf16* hidden = (__bf16*)(ws + 4096 + 512 * 1024);    // [1024][256]

  hipMemsetAsync(stats, 0, 100 * sizeof(float), stream);
  kg_stats_kernel<<<512, 256, 0, stream>>>(kg_map, stats);
  kg_finalize_kernel<<<1, 64, 0, stream>>>(stats, musd);
  gru_kernel<<<64, 256, 0, stream>>>(seq, tlen, item_emb, Wih, Whh, bih, bhh, mlp_in);
  bk_kernel<<<BB, 64, 0, stream>>>(seq, tlen, kg_map, musd, mlphW, mlphb, mlp_in);
  mlp_kernel<<<128, 256, 0, stream>>>(mlp_in, mlpW, mlpb, hidden);
  fc_kernel<<<5000, 256, 0, stream>>>(hidden, fcW, fcb, out);
}